// Round 4
// baseline (662.745 us; speedup 1.0000x reference)
//
#include <hip/hip_runtime.h>
#include <stdint.h>

#define NCH 12
#define DS 160
#define HS 160
#define WS 160
#define HW (HS * WS)
#define DHW (DS * HS * WS)   // 4,096,000 voxels

// Binning: 8^3-voxel bricks -> 20^3 = 8000 bins.
#define BIN_SHIFT 3
#define NBX 20
#define NBINS (NBX * NBX * NBX)
#define SCAN_T 1024

// ---------------------------------------------------------------------------
// bf16 helpers. Channel-last cell = 12 bf16 = 24 B = 6 uint32.
// ---------------------------------------------------------------------------
__device__ __forceinline__ uint32_t bf16_rne(float f) {
    uint32_t b = __float_as_uint(f);
    return (b + 0x7fffu + ((b >> 16) & 1u)) >> 16;
}

__device__ __forceinline__ void load_cell(const uint32_t* __restrict__ gt,
                                          int idx, uint32_t u[6]) {
    const uint2* p = (const uint2*)(gt + (size_t)idx * 6);  // 8-B aligned
    uint2 a = p[0], b = p[1], c = p[2];
    u[0] = a.x; u[1] = a.y; u[2] = b.x; u[3] = b.y; u[4] = c.x; u[5] = c.y;
}

__device__ __forceinline__ void acc_cell(const uint32_t u[6], float w,
                                         float acc[NCH]) {
#pragma unroll
    for (int k = 0; k < 6; ++k) {
        float lo = __uint_as_float(u[k] << 16);
        float hi = __uint_as_float(u[k] & 0xffff0000u);
        acc[2 * k]     = fmaf(w, lo, acc[2 * k]);
        acc[2 * k + 1] = fmaf(w, hi, acc[2 * k + 1]);
    }
}

// Shared coordinate math: point i -> grid-space px,py,pz.
__device__ __forceinline__ void point_coords(
    const float* __restrict__ xyz, int i,
    const float* __restrict__ xyz_min, const float* __restrict__ xyz_max,
    float& px, float& py, float& pz)
{
    float p0 = xyz[3 * i + 0];
    float p1 = xyz[3 * i + 1];
    float p2 = xyz[3 * i + 2];
    float u0 = (p0 - xyz_min[0]) / (xyz_max[0] - xyz_min[0]);
    float u1 = (p1 - xyz_min[1]) / (xyz_max[1] - xyz_min[1]);
    float u2 = (p2 - xyz_min[2]) / (xyz_max[2] - xyz_min[2]);
    // column 2 indexes W, column 1 indexes H, column 0 indexes D
    px = u2 * (float)(WS - 1);
    py = u1 * (float)(HS - 1);
    pz = u0 * (float)(DS - 1);
}

__device__ __forceinline__ int bin_of(float px, float py, float pz) {
    int x0 = min(max((int)floorf(px), 0), WS - 1);
    int y0 = min(max((int)floorf(py), 0), HS - 1);
    int z0 = min(max((int)floorf(pz), 0), DS - 1);
    return ((z0 >> BIN_SHIFT) * NBX + (y0 >> BIN_SHIFT)) * NBX + (x0 >> BIN_SHIFT);
}

// ---------------------------------------------------------------------------
// Kernel 1: transpose+convert [C, D*H*W] fp32 -> [D*H*W, 12] bf16.
// ---------------------------------------------------------------------------
__global__ __launch_bounds__(256) void transpose_bf16_kernel(
    const float* __restrict__ g, uint32_t* __restrict__ gt)
{
    int t = blockIdx.x * blockDim.x + threadIdx.x;   // voxels 4t..4t+3
    if (t >= DHW / 4) return;

    float vv[NCH][4];
#pragma unroll
    for (int c = 0; c < NCH; ++c) {
        float4 r = *(const float4*)(g + (size_t)c * DHW + 4 * (size_t)t);
        vv[c][0] = r.x; vv[c][1] = r.y; vv[c][2] = r.z; vv[c][3] = r.w;
    }

    uint32_t o[24];
#pragma unroll
    for (int j = 0; j < 4; ++j) {
#pragma unroll
        for (int k = 0; k < 6; ++k) {
            o[j * 6 + k] = bf16_rne(vv[2 * k][j]) | (bf16_rne(vv[2 * k + 1][j]) << 16);
        }
    }

    uint4* dst = (uint4*)(gt + (size_t)t * 24);
#pragma unroll
    for (int q = 0; q < 6; ++q)
        dst[q] = make_uint4(o[4 * q], o[4 * q + 1], o[4 * q + 2], o[4 * q + 3]);
}

// ---------------------------------------------------------------------------
// Binning pipeline
// ---------------------------------------------------------------------------
__global__ __launch_bounds__(256) void zero_hist_kernel(int* __restrict__ hist) {
    int i = blockIdx.x * blockDim.x + threadIdx.x;
    if (i < NBINS) hist[i] = 0;
}

__global__ __launch_bounds__(256) void hist_kernel(
    const float* __restrict__ xyz,
    const float* __restrict__ xyz_min,
    const float* __restrict__ xyz_max,
    int* __restrict__ hist, int n)
{
    int i = blockIdx.x * blockDim.x + threadIdx.x;
    if (i >= n) return;
    float px, py, pz;
    point_coords(xyz, i, xyz_min, xyz_max, px, py, pz);
    atomicAdd(&hist[bin_of(px, py, pz)], 1);
}

__global__ __launch_bounds__(SCAN_T) void scan_kernel(
    const int* __restrict__ hist,
    int* __restrict__ offsets,   // [NBINS+1]
    int* __restrict__ cursor)    // [NBINS]
{
    __shared__ int lds[SCAN_T];
    int t = threadIdx.x;
    const int PER = (NBINS + SCAN_T - 1) / SCAN_T;  // 8

    int s[PER];
    int local = 0;
#pragma unroll
    for (int k = 0; k < PER; ++k) {
        int idx = t * PER + k;
        int v = (idx < NBINS) ? hist[idx] : 0;
        s[k] = v;
        local += v;
    }
    lds[t] = local;
    __syncthreads();
    // Hillis-Steele inclusive scan over SCAN_T partials
    for (int off = 1; off < SCAN_T; off <<= 1) {
        int v = (t >= off) ? lds[t - off] : 0;
        __syncthreads();
        lds[t] += v;
        __syncthreads();
    }
    int base = lds[t] - local;  // exclusive prefix for this thread's chunk
#pragma unroll
    for (int k = 0; k < PER; ++k) {
        int idx = t * PER + k;
        if (idx < NBINS) {
            offsets[idx] = base;
            cursor[idx]  = base;
            base += s[k];
        }
    }
    if (t == SCAN_T - 1) offsets[NBINS] = base;
}

__global__ __launch_bounds__(256) void scatter_kernel(
    const float* __restrict__ xyz,
    const float* __restrict__ xyz_min,
    const float* __restrict__ xyz_max,
    int* __restrict__ cursor,
    float4* __restrict__ recs, int n)
{
    int i = blockIdx.x * blockDim.x + threadIdx.x;
    if (i >= n) return;
    float px, py, pz;
    point_coords(xyz, i, xyz_min, xyz_max, px, py, pz);
    int b = bin_of(px, py, pz);
    int pos = atomicAdd(&cursor[b], 1);
    recs[pos] = make_float4(px, py, pz, __uint_as_float((uint32_t)i));
}

__global__ __launch_bounds__(256) void sample_binned_kernel(
    const float4* __restrict__ recs,
    const uint32_t* __restrict__ gt,    // [D*H*W, 12] bf16 packed
    float* __restrict__ out, int n)
{
    int j = blockIdx.x * blockDim.x + threadIdx.x;
    if (j >= n) return;

    float4 r = recs[j];
    float px = r.x, py = r.y, pz = r.z;
    uint32_t orig = __float_as_uint(r.w);

    float x0f = floorf(px), y0f = floorf(py), z0f = floorf(pz);
    float fx = px - x0f, fy = py - y0f, fz = pz - z0f;

    int x0 = min(max((int)x0f, 0), WS - 1);
    int y0 = min(max((int)y0f, 0), HS - 1);
    int z0 = min(max((int)z0f, 0), DS - 1);
    int x1 = min(x0 + 1, WS - 1);
    int y1 = min(y0 + 1, HS - 1);
    int z1 = min(z0 + 1, DS - 1);

    float wx0 = 1.0f - fx, wx1 = fx;
    float wy0 = 1.0f - fy, wy1 = fy;
    float wz0 = 1.0f - fz, wz1 = fz;

    float w000 = wz0 * wy0 * wx0;
    float w001 = wz0 * wy0 * wx1;
    float w010 = wz0 * wy1 * wx0;
    float w011 = wz0 * wy1 * wx1;
    float w100 = wz1 * wy0 * wx0;
    float w101 = wz1 * wy0 * wx1;
    float w110 = wz1 * wy1 * wx0;
    float w111 = wz1 * wy1 * wx1;

    int zo0 = z0 * HW, zo1 = z1 * HW;
    int yo0 = y0 * WS, yo1 = y1 * WS;

    float acc[NCH];
#pragma unroll
    for (int c = 0; c < NCH; ++c) acc[c] = 0.0f;

    {
        uint32_t a[6], b[6];
        load_cell(gt, zo0 + yo0 + x0, a);
        load_cell(gt, zo0 + yo0 + x1, b);
        acc_cell(a, w000, acc);
        acc_cell(b, w001, acc);
    }
    {
        uint32_t a[6], b[6];
        load_cell(gt, zo0 + yo1 + x0, a);
        load_cell(gt, zo0 + yo1 + x1, b);
        acc_cell(a, w010, acc);
        acc_cell(b, w011, acc);
    }
    {
        uint32_t a[6], b[6];
        load_cell(gt, zo1 + yo0 + x0, a);
        load_cell(gt, zo1 + yo0 + x1, b);
        acc_cell(a, w100, acc);
        acc_cell(b, w101, acc);
    }
    {
        uint32_t a[6], b[6];
        load_cell(gt, zo1 + yo1 + x0, a);
        load_cell(gt, zo1 + yo1 + x1, b);
        acc_cell(a, w110, acc);
        acc_cell(b, w111, acc);
    }

    float4* o4 = (float4*)(out + (size_t)orig * NCH);
    o4[0] = make_float4(acc[0], acc[1], acc[2], acc[3]);
    o4[1] = make_float4(acc[4], acc[5], acc[6], acc[7]);
    o4[2] = make_float4(acc[8], acc[9], acc[10], acc[11]);
}

// ---------------------------------------------------------------------------
// Fallback 1: non-binned bf16 channel-last sample (round-3 kernel).
// ---------------------------------------------------------------------------
__global__ __launch_bounds__(256) void densegrid_sample_bf16_kernel(
    const float* __restrict__ xyz,
    const uint32_t* __restrict__ gt,
    const float* __restrict__ xyz_min,
    const float* __restrict__ xyz_max,
    float* __restrict__ out, int n)
{
    int i = blockIdx.x * blockDim.x + threadIdx.x;
    if (i >= n) return;

    float px, py, pz;
    point_coords(xyz, i, xyz_min, xyz_max, px, py, pz);

    float x0f = floorf(px), y0f = floorf(py), z0f = floorf(pz);
    float fx = px - x0f, fy = py - y0f, fz = pz - z0f;

    int x0 = min(max((int)x0f, 0), WS - 1);
    int y0 = min(max((int)y0f, 0), HS - 1);
    int z0 = min(max((int)z0f, 0), DS - 1);
    int x1 = min(x0 + 1, WS - 1);
    int y1 = min(y0 + 1, HS - 1);
    int z1 = min(z0 + 1, DS - 1);

    float wx0 = 1.0f - fx, wx1 = fx;
    float wy0 = 1.0f - fy, wy1 = fy;
    float wz0 = 1.0f - fz, wz1 = fz;

    float w000 = wz0 * wy0 * wx0, w001 = wz0 * wy0 * wx1;
    float w010 = wz0 * wy1 * wx0, w011 = wz0 * wy1 * wx1;
    float w100 = wz1 * wy0 * wx0, w101 = wz1 * wy0 * wx1;
    float w110 = wz1 * wy1 * wx0, w111 = wz1 * wy1 * wx1;

    int zo0 = z0 * HW, zo1 = z1 * HW;
    int yo0 = y0 * WS, yo1 = y1 * WS;

    float acc[NCH];
#pragma unroll
    for (int c = 0; c < NCH; ++c) acc[c] = 0.0f;

    {
        uint32_t a[6], b[6];
        load_cell(gt, zo0 + yo0 + x0, a);
        load_cell(gt, zo0 + yo0 + x1, b);
        acc_cell(a, w000, acc); acc_cell(b, w001, acc);
    }
    {
        uint32_t a[6], b[6];
        load_cell(gt, zo0 + yo1 + x0, a);
        load_cell(gt, zo0 + yo1 + x1, b);
        acc_cell(a, w010, acc); acc_cell(b, w011, acc);
    }
    {
        uint32_t a[6], b[6];
        load_cell(gt, zo1 + yo0 + x0, a);
        load_cell(gt, zo1 + yo0 + x1, b);
        acc_cell(a, w100, acc); acc_cell(b, w101, acc);
    }
    {
        uint32_t a[6], b[6];
        load_cell(gt, zo1 + yo1 + x0, a);
        load_cell(gt, zo1 + yo1 + x1, b);
        acc_cell(a, w110, acc); acc_cell(b, w111, acc);
    }

    float4* o4 = (float4*)(out + (size_t)i * NCH);
    o4[0] = make_float4(acc[0], acc[1], acc[2], acc[3]);
    o4[1] = make_float4(acc[4], acc[5], acc[6], acc[7]);
    o4[2] = make_float4(acc[8], acc[9], acc[10], acc[11]);
}

// ---------------------------------------------------------------------------
// Fallback 2: direct channel-first sample (round-0 kernel), no workspace.
// ---------------------------------------------------------------------------
__global__ __launch_bounds__(256) void densegrid_sample_chfirst_kernel(
    const float* __restrict__ xyz,
    const float* __restrict__ grid,
    const float* __restrict__ xyz_min,
    const float* __restrict__ xyz_max,
    float* __restrict__ out, int n)
{
    int i = blockIdx.x * blockDim.x + threadIdx.x;
    if (i >= n) return;

    float px, py, pz;
    point_coords(xyz, i, xyz_min, xyz_max, px, py, pz);

    float x0f = floorf(px), y0f = floorf(py), z0f = floorf(pz);
    float fx = px - x0f, fy = py - y0f, fz = pz - z0f;

    int x0 = min(max((int)x0f, 0), WS - 1);
    int y0 = min(max((int)y0f, 0), HS - 1);
    int z0 = min(max((int)z0f, 0), DS - 1);
    int x1 = min(x0 + 1, WS - 1);
    int y1 = min(y0 + 1, HS - 1);
    int z1 = min(z0 + 1, DS - 1);

    float wx0 = 1.0f - fx, wx1 = fx;
    float wy0 = 1.0f - fy, wy1 = fy;
    float wz0 = 1.0f - fz, wz1 = fz;

    float w000 = wz0 * wy0 * wx0, w001 = wz0 * wy0 * wx1;
    float w010 = wz0 * wy1 * wx0, w011 = wz0 * wy1 * wx1;
    float w100 = wz1 * wy0 * wx0, w101 = wz1 * wy0 * wx1;
    float w110 = wz1 * wy1 * wx0, w111 = wz1 * wy1 * wx1;

    int o00 = z0 * HW + y0 * WS;
    int o01 = z0 * HW + y1 * WS;
    int o10 = z1 * HW + y0 * WS;
    int o11 = z1 * HW + y1 * WS;

    float res[NCH];
#pragma unroll
    for (int c = 0; c < NCH; ++c) {
        const float* g = grid + (size_t)c * DHW;
        float acc = g[o00 + x0] * w000;
        acc = fmaf(g[o00 + x1], w001, acc);
        acc = fmaf(g[o01 + x0], w010, acc);
        acc = fmaf(g[o01 + x1], w011, acc);
        acc = fmaf(g[o10 + x0], w100, acc);
        acc = fmaf(g[o10 + x1], w101, acc);
        acc = fmaf(g[o11 + x0], w110, acc);
        acc = fmaf(g[o11 + x1], w111, acc);
        res[c] = acc;
    }
    float4* o4 = (float4*)(out + (size_t)i * NCH);
    o4[0] = make_float4(res[0], res[1], res[2], res[3]);
    o4[1] = make_float4(res[4], res[5], res[6], res[7]);
    o4[2] = make_float4(res[8], res[9], res[10], res[11]);
}

extern "C" void kernel_launch(void* const* d_in, const int* in_sizes, int n_in,
                              void* d_out, int out_size, void* d_ws, size_t ws_size,
                              hipStream_t stream) {
    const float* xyz     = (const float*)d_in[0];
    const float* grid    = (const float*)d_in[1];
    const float* xyz_min = (const float*)d_in[2];
    const float* xyz_max = (const float*)d_in[3];
    float* out = (float*)d_out;

    int n = in_sizes[0] / 3;
    int block = 256;
    int blocks = (n + block - 1) / block;

    // Workspace layout
    size_t gt_bytes   = (size_t)DHW * NCH * 2;            // 98,304,000
    size_t hist_off   = (gt_bytes + 255) & ~(size_t)255;
    size_t hist_bytes = (size_t)NBINS * 4;
    size_t offs_off   = hist_off + ((hist_bytes + 255) & ~(size_t)255);
    size_t offs_bytes = (size_t)(NBINS + 1) * 4;
    size_t curs_off   = offs_off + ((offs_bytes + 255) & ~(size_t)255);
    size_t curs_bytes = (size_t)NBINS * 4;
    size_t recs_off   = curs_off + ((curs_bytes + 255) & ~(size_t)255);
    size_t recs_bytes = (size_t)n * 16;
    size_t total_binned = recs_off + recs_bytes;          // ~132 MB

    if (ws_size >= total_binned) {
        uint8_t* ws = (uint8_t*)d_ws;
        uint32_t* gt  = (uint32_t*)(ws);
        int* hist     = (int*)(ws + hist_off);
        int* offsets  = (int*)(ws + offs_off);
        int* cursor   = (int*)(ws + curs_off);
        float4* recs  = (float4*)(ws + recs_off);

        int tthreads = DHW / 4;
        transpose_bf16_kernel<<<(tthreads + block - 1) / block, block, 0, stream>>>(grid, gt);
        zero_hist_kernel<<<(NBINS + block - 1) / block, block, 0, stream>>>(hist);
        hist_kernel<<<blocks, block, 0, stream>>>(xyz, xyz_min, xyz_max, hist, n);
        scan_kernel<<<1, SCAN_T, 0, stream>>>(hist, offsets, cursor);
        scatter_kernel<<<blocks, block, 0, stream>>>(xyz, xyz_min, xyz_max, cursor, recs, n);
        sample_binned_kernel<<<blocks, block, 0, stream>>>(recs, gt, out, n);
    } else if (ws_size >= gt_bytes) {
        uint32_t* gt = (uint32_t*)d_ws;
        int tthreads = DHW / 4;
        transpose_bf16_kernel<<<(tthreads + block - 1) / block, block, 0, stream>>>(grid, gt);
        densegrid_sample_bf16_kernel<<<blocks, block, 0, stream>>>(
            xyz, gt, xyz_min, xyz_max, out, n);
    } else {
        densegrid_sample_chfirst_kernel<<<blocks, block, 0, stream>>>(
            xyz, grid, xyz_min, xyz_max, out, n);
    }
}